// Round 1
// baseline (514.880 us; speedup 1.0000x reference)
//
#include <hip/hip_runtime.h>
#include <math.h>

#define Bn 2
#define Cn 256
#define Nn 13824
#define NHn 4
#define Pn 64
#define Gn 8
#define NCH 54      // Nn/256

// ---------------- pos transpose [N,C] -> [C,N] ----------------
__global__ __launch_bounds__(256) void k_transpose_pos(const float* __restrict__ pos,
                                                       float* __restrict__ posT) {
  __shared__ float tile[64][65];
  int n0 = blockIdx.x * 64;
  int c0 = blockIdx.y * 64;
  int tc = threadIdx.x & 63;
  int tr = threadIdx.x >> 6;
  #pragma unroll
  for (int k = 0; k < 16; k++) {
    int n = tr + k * 4;
    tile[n][tc] = pos[(size_t)(n0 + n) * Cn + c0 + tc];
  }
  __syncthreads();
  #pragma unroll
  for (int k = 0; k < 16; k++) {
    int c = tr + k * 4;
    posT[(size_t)(c0 + c) * Nn + n0 + tc] = tile[tc][c];
  }
}

// ---------------- grouped 1x1x1 conv (optional fused inorm+lrelu on input) ----
template <bool NORM>
__global__ __launch_bounds__(256) void k_gconv(const float* __restrict__ src,
                                               const float* __restrict__ wt,
                                               const float* __restrict__ bias,
                                               const float* __restrict__ stats,
                                               float* __restrict__ dst) {
  int chunk = blockIdx.x, g = blockIdx.y, b = blockIdx.z;
  int t = threadIdx.x;
  int n = chunk * 256 + t;
  __shared__ float ws[32][32];
  __shared__ float ms[32], rs[32], bs[32];
  #pragma unroll
  for (int i = 0; i < 4; i++) {
    int e = t + 256 * i;
    ws[e >> 5][e & 31] = wt[g * 1024 + e];
  }
  if (t < 32) {
    bs[t] = bias[g * 32 + t];
    if (NORM) {
      ms[t] = stats[(b * Cn + g * 32 + t) * 2 + 0];
      rs[t] = stats[(b * Cn + g * 32 + t) * 2 + 1];
    }
  }
  __syncthreads();
  float in[32];
  const float* sp = src + ((size_t)b * Cn + g * 32) * Nn + n;
  #pragma unroll
  for (int i = 0; i < 32; i++) {
    float v = sp[(size_t)i * Nn];
    if (NORM) {
      v = (v - ms[i]) * rs[i];
      v = v >= 0.f ? v : 0.01f * v;
    }
    in[i] = v;
  }
  float* dp = dst + ((size_t)b * Cn + g * 32) * Nn + n;
  #pragma unroll
  for (int o = 0; o < 32; o++) {
    float acc = bs[o];
    #pragma unroll
    for (int i = 0; i < 32; i++) acc = fmaf(in[i], ws[i][o], acc);
    dp[(size_t)o * Nn] = acc;
  }
}

// ---------------- per (b,c) row mean/rstd over N ----------------
__global__ __launch_bounds__(256) void k_rowstats(const float* __restrict__ src,
                                                  float* __restrict__ stats) {
  int row = blockIdx.x;
  const float4* p = (const float4*)(src + (size_t)row * Nn);
  float s = 0.f, s2 = 0.f;
  for (int i = threadIdx.x; i < Nn / 4; i += 256) {
    float4 v = p[i];
    s += v.x + v.y + v.z + v.w;
    s2 += v.x * v.x + v.y * v.y + v.z * v.z + v.w * v.w;
  }
  #pragma unroll
  for (int off = 32; off > 0; off >>= 1) {
    s += __shfl_down(s, off);
    s2 += __shfl_down(s2, off);
  }
  __shared__ float r1[4], r2[4];
  int w = threadIdx.x >> 6;
  if ((threadIdx.x & 63) == 0) { r1[w] = s; r2[w] = s2; }
  __syncthreads();
  if (threadIdx.x == 0) {
    s = r1[0] + r1[1] + r1[2] + r1[3];
    s2 = r2[0] + r2[1] + r2[2] + r2[3];
    float m = s * (1.f / Nn);
    float var = s2 * (1.f / Nn) - m * m;
    stats[row * 2 + 0] = m;
    stats[row * 2 + 1] = rsqrtf(var + 1e-5f);
  }
}

// ---------------- xc = lrelu(inorm(t3) + xf) ----------------
__global__ __launch_bounds__(256) void k_resid(const float* __restrict__ t3,
                                               const float* __restrict__ stats,
                                               const float* __restrict__ xf,
                                               float* __restrict__ xc) {
  size_t i = (size_t)blockIdx.x * 256 + threadIdx.x;   // float4 index over B*C*N/4
  size_t row = i / (Nn / 4);
  float m = stats[row * 2], r = stats[row * 2 + 1];
  float4 a = ((const float4*)t3)[i];
  float4 x = ((const float4*)xf)[i];
  float4 o;
  o.x = (a.x - m) * r + x.x; o.x = o.x >= 0.f ? o.x : 0.01f * o.x;
  o.y = (a.y - m) * r + x.y; o.y = o.y >= 0.f ? o.y : 0.01f * o.y;
  o.z = (a.z - m) * r + x.z; o.z = o.z >= 0.f ? o.z : 0.01f * o.z;
  o.w = (a.w - m) * r + x.w; o.w = o.w >= 0.f ? o.w : 0.01f * o.w;
  ((float4*)xc)[i] = o;
}

// ---------------- per-token LN stats for xf-path and xc-path (merged) --------
__global__ __launch_bounds__(256) void k_tokenstats(const float* __restrict__ xf,
                                                    const float* __restrict__ xc,
                                                    const float* __restrict__ posT,
                                                    float* __restrict__ tsx,
                                                    float* __restrict__ tsc) {
  int b = blockIdx.y;
  int n = blockIdx.x * 256 + threadIdx.x;
  float s1 = 0, q1 = 0, s2 = 0, q2 = 0;
  for (int c = 0; c < Cn; c++) {
    float p = posT[(size_t)c * Nn + n];
    float a = xf[((size_t)b * Cn + c) * Nn + n] + p;
    float d = xc[((size_t)b * Cn + c) * Nn + n] + p;
    s1 += a; q1 += a * a;
    s2 += d; q2 += d * d;
  }
  float m1 = s1 * (1.f / Cn), v1 = q1 * (1.f / Cn) - m1 * m1;
  float m2 = s2 * (1.f / Cn), v2 = q2 * (1.f / Cn) - m2 * m2;
  tsx[((size_t)b * Nn + n) * 2 + 0] = m1;
  tsx[((size_t)b * Nn + n) * 2 + 1] = rsqrtf(v1 + 1e-5f);
  tsc[((size_t)b * Nn + n) * 2 + 0] = m2;
  tsc[((size_t)b * Nn + n) * 2 + 1] = rsqrtf(v2 + 1e-5f);
}

// ---------------- LN apply -> [C,N] layout ----------------
__global__ __launch_bounds__(256) void k_ln_apply(const float* __restrict__ src,
                                                  const float* __restrict__ posT,
                                                  const float* __restrict__ ts,
                                                  const float* __restrict__ g,
                                                  const float* __restrict__ beta,
                                                  float* __restrict__ dst) {
  size_t i = (size_t)blockIdx.x * 256 + threadIdx.x;   // float4 idx over B*C*N/4
  size_t bc = i / (Nn / 4);
  int c = (int)(bc % Cn);
  int b = (int)(bc / Cn);
  int n4 = (int)(i % (Nn / 4)) * 4;
  float4 s = ((const float4*)src)[i];
  float4 p = ((const float4*)posT)[(size_t)c * (Nn / 4) + (i % (Nn / 4))];
  float gg = g[c], bb = beta[c];
  const float* tp = ts + ((size_t)b * Nn + n4) * 2;
  float4 o;
  o.x = (s.x + p.x - tp[0]) * tp[1] * gg + bb;
  o.y = (s.y + p.y - tp[2]) * tp[3] * gg + bb;
  o.z = (s.z + p.z - tp[4]) * tp[5] * gg + bb;
  o.w = (s.w + p.w - tp[6]) * tp[7] * gg + bb;
  ((float4*)dst)[i] = o;
}

// ---------------- q = x_n @ w_qkv[:, 0:256]  (A in [C,N], out token-major) ---
__global__ __launch_bounds__(256) void k_sgemm_q(const float* __restrict__ A,
                                                 const float* __restrict__ W,
                                                 float* __restrict__ q) {
  int b = blockIdx.z;
  int n0 = blockIdx.x * 64, j0 = blockIdx.y * 64;
  __shared__ float As[16][64];
  __shared__ float Ws[16][64];
  int t = threadIdx.x, tx = t & 15, ty = t >> 4;
  float acc[4][4] = {};
  const float* Ab = A + (size_t)b * Cn * Nn;
  for (int k0 = 0; k0 < Cn; k0 += 16) {
    *(float4*)(&As[ty][tx * 4]) = *(const float4*)(Ab + (size_t)(k0 + ty) * Nn + n0 + tx * 4);
    *(float4*)(&Ws[ty][tx * 4]) = *(const float4*)(W + (size_t)(k0 + ty) * 768 + j0 + tx * 4);
    __syncthreads();
    #pragma unroll
    for (int kk = 0; kk < 16; kk++) {
      float4 av = *(const float4*)(&As[kk][ty * 4]);
      float4 wv = *(const float4*)(&Ws[kk][tx * 4]);
      float a_[4] = {av.x, av.y, av.z, av.w};
      float w_[4] = {wv.x, wv.y, wv.z, wv.w};
      #pragma unroll
      for (int i = 0; i < 4; i++)
        #pragma unroll
        for (int j = 0; j < 4; j++) acc[i][j] = fmaf(a_[i], w_[j], acc[i][j]);
    }
    __syncthreads();
  }
  #pragma unroll
  for (int i = 0; i < 4; i++) {
    float4 v = {acc[i][0], acc[i][1], acc[i][2], acc[i][3]};
    *(float4*)(q + ((size_t)b * Nn + n0 + ty * 4 + i) * Cn + j0 + tx * 4) = v;
  }
}

// ---------------- xe split-K partial: xe[b,c,p] = sum_n xnT[b,c,n]*w_e[n,p] --
__global__ __launch_bounds__(256) void k_xe_partial(const float* __restrict__ A,
                                                    const float* __restrict__ We,
                                                    float* __restrict__ part) {
  int chunk = blockIdx.x, ct = blockIdx.y, b = blockIdx.z;
  int c0 = ct * 64, nb = chunk * 256;
  __shared__ float As[64][17];
  __shared__ float Ws[16][64];
  int t = threadIdx.x, tx = t & 15, ty = t >> 4;
  float acc[4][4] = {};
  const float* Ab = A + (size_t)b * Cn * Nn;
  for (int k0 = 0; k0 < 256; k0 += 16) {
    {
      int cc = t >> 2, kk0 = (t & 3) * 4;
      float4 v = *(const float4*)(Ab + (size_t)(c0 + cc) * Nn + nb + k0 + kk0);
      As[cc][kk0 + 0] = v.x; As[cc][kk0 + 1] = v.y;
      As[cc][kk0 + 2] = v.z; As[cc][kk0 + 3] = v.w;
    }
    *(float4*)(&Ws[ty][tx * 4]) = *(const float4*)(We + (size_t)(nb + k0 + ty) * Pn + tx * 4);
    __syncthreads();
    #pragma unroll
    for (int kk = 0; kk < 16; kk++) {
      float a_[4], w_[4];
      #pragma unroll
      for (int i = 0; i < 4; i++) a_[i] = As[ty * 4 + i][kk];
      float4 wv = *(const float4*)(&Ws[kk][tx * 4]);
      w_[0] = wv.x; w_[1] = wv.y; w_[2] = wv.z; w_[3] = wv.w;
      #pragma unroll
      for (int i = 0; i < 4; i++)
        #pragma unroll
        for (int j = 0; j < 4; j++) acc[i][j] = fmaf(a_[i], w_[j], acc[i][j]);
    }
    __syncthreads();
  }
  #pragma unroll
  for (int i = 0; i < 4; i++) {
    float4 v = {acc[i][0], acc[i][1], acc[i][2], acc[i][3]};
    *(float4*)(part + (((size_t)(b * NCH + chunk) * Cn + c0 + ty * 4 + i) * Pn) + tx * 4) = v;
  }
}

__global__ __launch_bounds__(256) void k_xe_reduce(const float* __restrict__ part,
                                                   float* __restrict__ xe) {
  int i = blockIdx.x * 256 + threadIdx.x;     // B*C*P = 32768
  int b = i / (Cn * Pn);
  int cp = i % (Cn * Pn);
  float s = 0.f;
  for (int ch = 0; ch < NCH; ch++) s += part[(size_t)(b * NCH + ch) * Cn * Pn + cp];
  xe[i] = s;
}

// ---------------- k_proj/v_proj[b,hd,p] = b_e[p] + sum_c xe[b,c,p]*wqkv[c,off+hd]
__global__ __launch_bounds__(256) void k_kvproj(const float* __restrict__ xe,
                                                const float* __restrict__ wqkv,
                                                const float* __restrict__ be,
                                                float* __restrict__ kvp) {
  int hd = blockIdx.x * 4 + (threadIdx.x >> 6);
  int kv = blockIdx.y, b = blockIdx.z;
  int p = threadIdx.x & 63;
  int col = (kv + 1) * Cn + hd;
  float acc = be[p];
  for (int c = 0; c < Cn; c++)
    acc = fmaf(xe[((size_t)b * Cn + c) * Pn + p], wqkv[(size_t)c * 768 + col], acc);
  kvp[(((size_t)b * 2 + kv) * Cn + hd) * Pn + p] = acc;
}

// ---------------- q-norm partial sums and scale ----------------
__global__ __launch_bounds__(256) void k_qsq(const float* __restrict__ q,
                                             float* __restrict__ part) {
  int b = blockIdx.y, chunk = blockIdx.x, c = threadIdx.x;
  const float* qb = q + (size_t)b * Nn * Cn + (size_t)chunk * 256 * Cn + c;
  float s = 0.f;
  for (int n = 0; n < 256; n++) { float v = qb[(size_t)n * Cn]; s = fmaf(v, v, s); }
  part[(size_t)(b * NCH + chunk) * Cn + c] = s;
}

__global__ __launch_bounds__(256) void k_qscale(const float* __restrict__ part,
                                                float* __restrict__ scale) {
  int i = blockIdx.x * 256 + threadIdx.x;     // B*C = 512
  int b = i / Cn, c = i % Cn;
  float s = 0.f;
  for (int ch = 0; ch < NCH; ch++) s += part[(size_t)(b * NCH + ch) * Cn + c];
  scale[i] = 1.f / fmaxf(sqrtf(s), 1e-12f);
}

// ---------------- pooled[b,c] = b_pool + sum_n xcnT[b,c,n]*w_pool[n] ---------
__global__ __launch_bounds__(256) void k_pooled(const float* __restrict__ xcnT,
                                                const float* __restrict__ wpool,
                                                const float* __restrict__ bpool,
                                                float* __restrict__ pooled) {
  int row = blockIdx.x;                       // b*C + c
  const float4* p = (const float4*)(xcnT + (size_t)row * Nn);
  const float4* wp = (const float4*)wpool;
  float s = 0.f;
  for (int i = threadIdx.x; i < Nn / 4; i += 256) {
    float4 v = p[i]; float4 w = wp[i];
    s += v.x * w.x + v.y * w.y + v.z * w.z + v.w * w.w;
  }
  #pragma unroll
  for (int off = 32; off > 0; off >>= 1) s += __shfl_down(s, off);
  __shared__ float r1[4];
  int w = threadIdx.x >> 6;
  if ((threadIdx.x & 63) == 0) r1[w] = s;
  __syncthreads();
  if (threadIdx.x == 0) pooled[row] = r1[0] + r1[1] + r1[2] + r1[3] + bpool[0];
}

// ---------------- gate = sigmoid(relu(pooled @ wfc1) @ wfc2) ----------------
__global__ __launch_bounds__(256) void k_gate(const float* __restrict__ pooled,
                                              const float* __restrict__ wfc1,
                                              const float* __restrict__ wfc2,
                                              float* __restrict__ gate) {
  int b = blockIdx.x, t = threadIdx.x;
  __shared__ float pl[256], h1[64];
  pl[t] = pooled[b * Cn + t];
  __syncthreads();
  if (t < 64) {
    float s = 0.f;
    for (int c = 0; c < Cn; c++) s = fmaf(pl[c], wfc1[c * 64 + t], s);
    h1[t] = fmaxf(s, 0.f);
  }
  __syncthreads();
  float s = 0.f;
  for (int j = 0; j < 64; j++) s = fmaf(h1[j], wfc2[j * Cn + t], s);
  gate[b * Cn + t] = 1.f / (1.f + __expf(-s));
}

__global__ __launch_bounds__(256) void k_w2g(const float* __restrict__ gate,
                                             const float* __restrict__ w2,
                                             float* __restrict__ w2g) {
  int i = blockIdx.x * 256 + threadIdx.x;     // B*C*128
  int b = i / (Cn * 128);
  int cj = i % (Cn * 128);
  int c = cj / 128;
  w2g[i] = gate[b * Cn + c] * w2[cj];
}

// ---------------- spatial attention: per-token softmax(qn.kp*T) @ vp --------
__global__ __launch_bounds__(256) void k_attn(const float* __restrict__ q,
                                              const float* __restrict__ scale,
                                              const float* __restrict__ kvp,
                                              const float* __restrict__ temp,
                                              float* __restrict__ xsa) {
  int chunk = blockIdx.x, h = blockIdx.y, b = blockIdx.z;
  int t = threadIdx.x;
  __shared__ float kp[64][64];
  __shared__ float vp[64][64];
  __shared__ float sc[64];
  const float* kpg = kvp + (((size_t)b * 2 + 0) * Cn + h * 64) * Pn;
  const float* vpg = kvp + (((size_t)b * 2 + 1) * Cn + h * 64) * Pn;
  #pragma unroll
  for (int e = t * 4; e < 4096; e += 1024) {
    *(float4*)(&kp[e >> 6][e & 63]) = *(const float4*)(kpg + e);
    *(float4*)(&vp[e >> 6][e & 63]) = *(const float4*)(vpg + e);
  }
  if (t < 64) sc[t] = scale[b * Cn + h * 64 + t];
  __syncthreads();
  float T = temp[h];
  int n = chunk * 256 + t;
  float qr[64];
  const float* qp = q + ((size_t)b * Nn + n) * Cn + h * 64;
  #pragma unroll
  for (int d0 = 0; d0 < 64; d0 += 4) {
    float4 v = *(const float4*)(qp + d0);
    qr[d0 + 0] = v.x * sc[d0 + 0];
    qr[d0 + 1] = v.y * sc[d0 + 1];
    qr[d0 + 2] = v.z * sc[d0 + 2];
    qr[d0 + 3] = v.w * sc[d0 + 3];
  }
  float s[64];
  #pragma unroll
  for (int p0 = 0; p0 < 64; p0 += 4) {
    float a0 = 0, a1 = 0, a2 = 0, a3 = 0;
    #pragma unroll
    for (int d = 0; d < 64; d++) {
      float4 kv = *(const float4*)(&kp[d][p0]);
      float qd = qr[d];
      a0 = fmaf(qd, kv.x, a0);
      a1 = fmaf(qd, kv.y, a1);
      a2 = fmaf(qd, kv.z, a2);
      a3 = fmaf(qd, kv.w, a3);
    }
    s[p0 + 0] = a0 * T; s[p0 + 1] = a1 * T; s[p0 + 2] = a2 * T; s[p0 + 3] = a3 * T;
  }
  float mx = -1e30f;
  #pragma unroll
  for (int p = 0; p < 64; p++) mx = fmaxf(mx, s[p]);
  float den = 0.f;
  #pragma unroll
  for (int p = 0; p < 64; p++) { float e = __expf(s[p] - mx); s[p] = e; den += e; }
  float inv = 1.f / den;
  #pragma unroll
  for (int p = 0; p < 64; p++) s[p] *= inv;
  // scrambled write: flat = (d*NH + h)*N + n
  float* ob = xsa + (size_t)b * Nn * Cn + (size_t)h * Nn + n;
  #pragma unroll
  for (int d = 0; d < 64; d++) {
    float a = 0.f;
    #pragma unroll
    for (int p0 = 0; p0 < 64; p0 += 4) {
      float4 vv = *(const float4*)(&vp[d][p0]);
      a = fmaf(s[p0 + 0], vv.x, a);
      a = fmaf(s[p0 + 1], vv.y, a);
      a = fmaf(s[p0 + 2], vv.z, a);
      a = fmaf(s[p0 + 3], vv.w, a);
    }
    ob[(size_t)d * NHn * Nn] = a;
  }
}

// ---------------- out rows [0,128): x_SA @ w_out1, fused epilogue+transpose --
__global__ __launch_bounds__(256) void k_out1(const float* __restrict__ xsa,
                                              const float* __restrict__ w1,
                                              const float* __restrict__ b1,
                                              const float* __restrict__ xnT,
                                              const float* __restrict__ gamma,
                                              float* __restrict__ out) {
  int b = blockIdx.z, n0 = blockIdx.x * 64, j0 = blockIdx.y * 64;
  __shared__ float As[16][68];
  __shared__ float Ws[16][64];
  __shared__ float Ot[64][68];
  int t = threadIdx.x, tx = t & 15, ty = t >> 4;
  float acc[4][4] = {};
  for (int k0 = 0; k0 < Cn; k0 += 16) {
    {
      int nn = t >> 2, kk0 = (t & 3) * 4;
      float4 v = *(const float4*)(xsa + ((size_t)b * Nn + n0 + nn) * Cn + k0 + kk0);
      As[kk0 + 0][nn] = v.x; As[kk0 + 1][nn] = v.y;
      As[kk0 + 2][nn] = v.z; As[kk0 + 3][nn] = v.w;
    }
    *(float4*)(&Ws[ty][tx * 4]) = *(const float4*)(w1 + (size_t)(k0 + ty) * 128 + j0 + tx * 4);
    __syncthreads();
    #pragma unroll
    for (int kk = 0; kk < 16; kk++) {
      float4 av = *(const float4*)(&As[kk][ty * 4]);
      float4 wv = *(const float4*)(&Ws[kk][tx * 4]);
      float a_[4] = {av.x, av.y, av.z, av.w};
      float w_[4] = {wv.x, wv.y, wv.z, wv.w};
      #pragma unroll
      for (int i = 0; i < 4; i++)
        #pragma unroll
        for (int j = 0; j < 4; j++) acc[i][j] = fmaf(a_[i], w_[j], acc[i][j]);
    }
    __syncthreads();
  }
  #pragma unroll
  for (int j = 0; j < 4; j++) {
    float4 v = {acc[0][j], acc[1][j], acc[2][j], acc[3][j]};
    *(float4*)(&Ot[tx * 4 + j][ty * 4]) = v;
  }
  __syncthreads();
  int jj = t >> 2, nb = (t & 3) * 16;
  int c = j0 + jj;
  float gm = gamma[c];
  float bias = b1[j0 + jj];
  const float* xn = xnT + ((size_t)b * Cn + c) * Nn + n0 + nb;
  float* op = out + ((size_t)b * Cn + c) * Nn + n0 + nb;
  #pragma unroll
  for (int m = 0; m < 4; m++) {
    float4 xv = *(const float4*)(xn + m * 4);
    float4 ov = *(const float4*)(&Ot[jj][nb + m * 4]);
    float4 o;
    o.x = xv.x + gm * (ov.x + bias);
    o.y = xv.y + gm * (ov.y + bias);
    o.z = xv.z + gm * (ov.z + bias);
    o.w = xv.w + gm * (ov.w + bias);
    *(float4*)(op + m * 4) = o;
  }
}

// ---------------- out rows [128,256): xc_n*gate @ w_out2 (gate folded in W) --
__global__ __launch_bounds__(256) void k_out2(const float* __restrict__ xcnT,
                                              const float* __restrict__ w2g,
                                              const float* __restrict__ b2,
                                              const float* __restrict__ xnT,
                                              const float* __restrict__ gamma,
                                              float* __restrict__ out) {
  int b = blockIdx.z, n0 = blockIdx.x * 64, j0 = blockIdx.y * 64;
  __shared__ float As[16][64];
  __shared__ float Ws[16][64];
  __shared__ float Ot[64][68];
  int t = threadIdx.x, tx = t & 15, ty = t >> 4;
  float acc[4][4] = {};
  const float* Ab = xcnT + (size_t)b * Cn * Nn;
  const float* Wb = w2g + (size_t)b * Cn * 128;
  for (int k0 = 0; k0 < Cn; k0 += 16) {
    *(float4*)(&As[ty][tx * 4]) = *(const float4*)(Ab + (size_t)(k0 + ty) * Nn + n0 + tx * 4);
    *(float4*)(&Ws[ty][tx * 4]) = *(const float4*)(Wb + (size_t)(k0 + ty) * 128 + j0 + tx * 4);
    __syncthreads();
    #pragma unroll
    for (int kk = 0; kk < 16; kk++) {
      float4 av = *(const float4*)(&As[kk][ty * 4]);
      float4 wv = *(const float4*)(&Ws[kk][tx * 4]);
      float a_[4] = {av.x, av.y, av.z, av.w};
      float w_[4] = {wv.x, wv.y, wv.z, wv.w};
      #pragma unroll
      for (int i = 0; i < 4; i++)
        #pragma unroll
        for (int j = 0; j < 4; j++) acc[i][j] = fmaf(a_[i], w_[j], acc[i][j]);
    }
    __syncthreads();
  }
  #pragma unroll
  for (int j = 0; j < 4; j++) {
    float4 v = {acc[0][j], acc[1][j], acc[2][j], acc[3][j]};
    *(float4*)(&Ot[tx * 4 + j][ty * 4]) = v;
  }
  __syncthreads();
  int jj = t >> 2, nb = (t & 3) * 16;
  int c = 128 + j0 + jj;
  float gm = gamma[c];
  float bias = b2[j0 + jj];
  const float* xn = xnT + ((size_t)b * Cn + c) * Nn + n0 + nb;
  float* op = out + ((size_t)b * Cn + c) * Nn + n0 + nb;
  #pragma unroll
  for (int m = 0; m < 4; m++) {
    float4 xv = *(const float4*)(xn + m * 4);
    float4 ov = *(const float4*)(&Ot[jj][nb + m * 4]);
    float4 o;
    o.x = xv.x + gm * (ov.x + bias);
    o.y = xv.y + gm * (ov.y + bias);
    o.z = xv.z + gm * (ov.z + bias);
    o.w = xv.w + gm * (ov.w + bias);
    *(float4*)(op + m * 4) = o;
  }
}

extern "C" void kernel_launch(void* const* d_in, const int* in_sizes, int n_in,
                              void* d_out, int out_size, void* d_ws, size_t ws_size,
                              hipStream_t stream) {
  const float* x      = (const float*)d_in[0];
  const float* pos    = (const float*)d_in[1];
  const float* ln_g   = (const float*)d_in[2];
  const float* ln_b   = (const float*)d_in[3];
  const float* gamma  = (const float*)d_in[4];
  const float* temp2  = (const float*)d_in[5];
  const float* w_qkv  = (const float*)d_in[6];
  const float* w_e    = (const float*)d_in[7];
  const float* b_e    = (const float*)d_in[8];
  const float* w_pool = (const float*)d_in[9];
  const float* b_pool = (const float*)d_in[10];
  const float* w_fc1  = (const float*)d_in[11];
  const float* w_fc2  = (const float*)d_in[12];
  const float* w_out1 = (const float*)d_in[13];
  const float* b_out1 = (const float*)d_in[14];
  const float* w_out2 = (const float*)d_in[15];
  const float* b_out2 = (const float*)d_in[16];
  const float* w_c1   = (const float*)d_in[17];
  const float* b_c1   = (const float*)d_in[18];
  const float* w_c2   = (const float*)d_in[19];
  const float* b_c2   = (const float*)d_in[20];
  (void)in_sizes; (void)n_in; (void)out_size; (void)ws_size;
  float* out = (float*)d_out;
  float* ws = (float*)d_ws;

  const size_t SZf = (size_t)Bn * Cn * Nn;  // 7,077,888 floats
  const size_t NCf = (size_t)Nn * Cn;       // 3,538,944 floats
  float* t1   = ws;                // later reused as xc
  float* t3   = ws + SZf;          // later reused as xnT
  float* xcnT = ws + 2 * SZf;
  float* qb   = ws + 3 * SZf;
  float* xsa  = ws + 4 * SZf;
  float* posT = ws + 5 * SZf;
  float* sm   = posT + NCf;
  float* stats1 = sm;
  float* stats3 = sm + 1024;
  float* tsx    = sm + 2048;
  float* tsc    = sm + 57344;
  float* qpart  = sm + 112640;
  float* scaleb = sm + 140288;
  float* xepart = sm + 140800;
  float* xe     = sm + 1910272;
  float* kvp    = sm + 1943040;
  float* pooled = sm + 2008576;
  float* gateb  = sm + 2009088;
  float* w2g    = sm + 2009600;

  float* xc  = t1;
  float* xnT = t3;

  k_transpose_pos<<<dim3(216, 4), 256, 0, stream>>>(pos, posT);
  k_gconv<false><<<dim3(NCH, Gn, Bn), 256, 0, stream>>>(x, w_c1, b_c1, nullptr, t1);
  k_rowstats<<<dim3(Bn * Cn), 256, 0, stream>>>(t1, stats1);
  k_gconv<true><<<dim3(NCH, Gn, Bn), 256, 0, stream>>>(t1, w_c2, b_c2, stats1, t3);
  k_rowstats<<<dim3(Bn * Cn), 256, 0, stream>>>(t3, stats3);
  k_resid<<<dim3(6912), 256, 0, stream>>>(t3, stats3, x, xc);
  k_tokenstats<<<dim3(NCH, Bn), 256, 0, stream>>>(x, xc, posT, tsx, tsc);
  k_ln_apply<<<dim3(6912), 256, 0, stream>>>(x, posT, tsx, ln_g, ln_b, xnT);
  k_ln_apply<<<dim3(6912), 256, 0, stream>>>(xc, posT, tsc, ln_g, ln_b, xcnT);
  k_sgemm_q<<<dim3(216, 4, Bn), 256, 0, stream>>>(xnT, w_qkv, qb);
  k_qsq<<<dim3(NCH, Bn), 256, 0, stream>>>(qb, qpart);
  k_qscale<<<dim3(2), 256, 0, stream>>>(qpart, scaleb);
  k_xe_partial<<<dim3(NCH, 4, Bn), 256, 0, stream>>>(xnT, w_e, xepart);
  k_xe_reduce<<<dim3(128), 256, 0, stream>>>(xepart, xe);
  k_kvproj<<<dim3(64, 2, Bn), 256, 0, stream>>>(xe, w_qkv, b_e, kvp);
  k_pooled<<<dim3(Bn * Cn), 256, 0, stream>>>(xcnT, w_pool, b_pool, pooled);
  k_gate<<<dim3(Bn), 256, 0, stream>>>(pooled, w_fc1, w_fc2, gateb);
  k_w2g<<<dim3(256), 256, 0, stream>>>(gateb, w_out2, w2g);
  k_attn<<<dim3(NCH, NHn, Bn), 256, 0, stream>>>(qb, scaleb, kvp, temp2, xsa);
  k_out1<<<dim3(216, 2, Bn), 256, 0, stream>>>(xsa, w_out1, b_out1, xnT, gamma, out);
  k_out2<<<dim3(216, 2, Bn), 256, 0, stream>>>(xcnT, w2g, b_out2, xnT, gamma, out);
}

// Round 2
// 390.701 us; speedup vs baseline: 1.3178x; 1.3178x over previous
//
#include <hip/hip_runtime.h>
#include <hip/hip_bf16.h>
#include <math.h>

#define Bn 2
#define Cn 256
#define Nn 13824
#define NHn 4
#define Pn 64
#define Gn 8
#define NCH 54      // Nn/256

typedef __bf16 bf16x8 __attribute__((ext_vector_type(8)));
typedef unsigned short us8v __attribute__((ext_vector_type(8)));
typedef float f32x4 __attribute__((ext_vector_type(4)));

__device__ __forceinline__ unsigned short f2bf(float f) {
  __hip_bfloat16 h = __float2bfloat16(f);
  return __builtin_bit_cast(unsigned short, h);
}
__device__ __forceinline__ float bf2f(unsigned short u) {
  return __builtin_bit_cast(float, ((unsigned)u) << 16);
}
__device__ __forceinline__ unsigned pk2(float a, float b) {
  return (unsigned)f2bf(a) | ((unsigned)f2bf(b) << 16);
}

// ---------------- pos transpose [N,C] -> [C,N] ----------------
__global__ __launch_bounds__(256) void k_transpose_pos(const float* __restrict__ pos,
                                                       float* __restrict__ posT) {
  __shared__ float tile[64][65];
  int n0 = blockIdx.x * 64;
  int c0 = blockIdx.y * 64;
  int tc = threadIdx.x & 63;
  int tr = threadIdx.x >> 6;
  #pragma unroll
  for (int k = 0; k < 16; k++) {
    int n = tr + k * 4;
    tile[n][tc] = pos[(size_t)(n0 + n) * Cn + c0 + tc];
  }
  __syncthreads();
  #pragma unroll
  for (int k = 0; k < 16; k++) {
    int c = tr + k * 4;
    posT[(size_t)(c0 + c) * Nn + n0 + tc] = tile[tc][c];
  }
}

// ---------------- weight convert: wqT[j][c], w1T[j][c] (bf16) ----------------
__global__ __launch_bounds__(256) void k_wcvt(const float* __restrict__ wqkv,
                                              const float* __restrict__ w1,
                                              unsigned short* __restrict__ wqT,
                                              unsigned short* __restrict__ w1T) {
  int j = blockIdx.x, c = threadIdx.x;
  if (j < 256) wqT[(size_t)j * 256 + c] = f2bf(wqkv[(size_t)c * 768 + j]);
  else w1T[(size_t)(j - 256) * 256 + c] = f2bf(w1[(size_t)c * 128 + (j - 256)]);
}

// ---------------- grouped 1x1x1 conv (optional fused inorm+lrelu on input) ----
template <bool NORM>
__global__ __launch_bounds__(256) void k_gconv(const float* __restrict__ src,
                                               const float* __restrict__ wt,
                                               const float* __restrict__ bias,
                                               const float* __restrict__ stats,
                                               float* __restrict__ dst) {
  int chunk = blockIdx.x, g = blockIdx.y, b = blockIdx.z;
  int t = threadIdx.x;
  int n = chunk * 256 + t;
  __shared__ float ws[32][32];
  __shared__ float ms[32], rs[32], bs[32];
  #pragma unroll
  for (int i = 0; i < 4; i++) {
    int e = t + 256 * i;
    ws[e >> 5][e & 31] = wt[g * 1024 + e];
  }
  if (t < 32) {
    bs[t] = bias[g * 32 + t];
    if (NORM) {
      ms[t] = stats[(b * Cn + g * 32 + t) * 2 + 0];
      rs[t] = stats[(b * Cn + g * 32 + t) * 2 + 1];
    }
  }
  __syncthreads();
  float in[32];
  const float* sp = src + ((size_t)b * Cn + g * 32) * Nn + n;
  #pragma unroll
  for (int i = 0; i < 32; i++) {
    float v = sp[(size_t)i * Nn];
    if (NORM) {
      v = (v - ms[i]) * rs[i];
      v = v >= 0.f ? v : 0.01f * v;
    }
    in[i] = v;
  }
  float* dp = dst + ((size_t)b * Cn + g * 32) * Nn + n;
  #pragma unroll
  for (int o = 0; o < 32; o++) {
    float acc = bs[o];
    #pragma unroll
    for (int i = 0; i < 32; i++) acc = fmaf(in[i], ws[i][o], acc);
    dp[(size_t)o * Nn] = acc;
  }
}

// ---------------- per (b,c) row mean/rstd over N ----------------
__global__ __launch_bounds__(256) void k_rowstats(const float* __restrict__ src,
                                                  float* __restrict__ stats) {
  int row = blockIdx.x;
  const float4* p = (const float4*)(src + (size_t)row * Nn);
  float s = 0.f, s2 = 0.f;
  for (int i = threadIdx.x; i < Nn / 4; i += 256) {
    float4 v = p[i];
    s += v.x + v.y + v.z + v.w;
    s2 += v.x * v.x + v.y * v.y + v.z * v.z + v.w * v.w;
  }
  #pragma unroll
  for (int off = 32; off > 0; off >>= 1) {
    s += __shfl_down(s, off);
    s2 += __shfl_down(s2, off);
  }
  __shared__ float r1[4], r2[4];
  int w = threadIdx.x >> 6;
  if ((threadIdx.x & 63) == 0) { r1[w] = s; r2[w] = s2; }
  __syncthreads();
  if (threadIdx.x == 0) {
    s = r1[0] + r1[1] + r1[2] + r1[3];
    s2 = r2[0] + r2[1] + r2[2] + r2[3];
    float m = s * (1.f / Nn);
    float var = s2 * (1.f / Nn) - m * m;
    stats[row * 2 + 0] = m;
    stats[row * 2 + 1] = rsqrtf(var + 1e-5f);
  }
}

// ---------------- fused: resid + tokenstats + LN-apply (both paths) ----------
// outputs: xnf  fp32 [b][c][n]   (exact path, epilogue add + xe GEMM)
//          xnbf bf16 [b][n][c]   (q GEMM operand)
//          xcnbf bf16 [b][n][c]  (pooled + out2 GEMM operand)
__global__ __launch_bounds__(256) void k_fused_ln(
    const float* __restrict__ x, const float* __restrict__ t3,
    const float* __restrict__ posT, const float* __restrict__ stats3,
    const float* __restrict__ g, const float* __restrict__ beta,
    float* __restrict__ xnf, unsigned short* __restrict__ xnbf,
    unsigned short* __restrict__ xcnbf) {
  int b = blockIdx.y, n0 = blockIdx.x * 64;
  int t = threadIdx.x, lane = t & 63, q = t >> 6;
  __shared__ float red[4][64][2];
  __shared__ unsigned short T[64][264];
  int n = n0 + lane;
  // ---- phase 1: x_n path ----
  float s = 0.f, ss = 0.f;
  #pragma unroll 4
  for (int ci = 0; ci < 64; ci++) {
    int c = q * 64 + ci;
    float v = x[((size_t)b * Cn + c) * Nn + n] + posT[(size_t)c * Nn + n];
    s += v; ss += v * v;
  }
  red[q][lane][0] = s; red[q][lane][1] = ss;
  __syncthreads();
  s = red[0][lane][0] + red[1][lane][0] + red[2][lane][0] + red[3][lane][0];
  ss = red[0][lane][1] + red[1][lane][1] + red[2][lane][1] + red[3][lane][1];
  float m1 = s * (1.f / 256.f);
  float r1 = rsqrtf(ss * (1.f / 256.f) - m1 * m1 + 1e-5f);
  #pragma unroll 4
  for (int ci = 0; ci < 64; ci++) {
    int c = q * 64 + ci;
    float v = x[((size_t)b * Cn + c) * Nn + n] + posT[(size_t)c * Nn + n];
    float o = (v - m1) * r1 * g[c] + beta[c];
    xnf[((size_t)b * Cn + c) * Nn + n] = o;
    T[lane][c] = f2bf(o);
  }
  __syncthreads();
  {
    int rn = t >> 2, cs = (t & 3) * 64;
    unsigned short* dst = xnbf + ((size_t)b * Nn + n0 + rn) * 256 + cs;
    #pragma unroll
    for (int i = 0; i < 8; i++) *(us8v*)(dst + i * 8) = *(const us8v*)(&T[rn][cs + i * 8]);
  }
  __syncthreads();
  // ---- phase 2: xc path ----
  s = 0.f; ss = 0.f;
  #pragma unroll 4
  for (int ci = 0; ci < 64; ci++) {
    int c = q * 64 + ci;
    float m3 = stats3[(b * Cn + c) * 2 + 0];
    float r3 = stats3[(b * Cn + c) * 2 + 1];
    float xv = x[((size_t)b * Cn + c) * Nn + n];
    float tv = t3[((size_t)b * Cn + c) * Nn + n];
    float xc = (tv - m3) * r3 + xv;
    xc = xc >= 0.f ? xc : 0.01f * xc;
    float v = xc + posT[(size_t)c * Nn + n];
    s += v; ss += v * v;
  }
  red[q][lane][0] = s; red[q][lane][1] = ss;
  __syncthreads();
  s = red[0][lane][0] + red[1][lane][0] + red[2][lane][0] + red[3][lane][0];
  ss = red[0][lane][1] + red[1][lane][1] + red[2][lane][1] + red[3][lane][1];
  float m2 = s * (1.f / 256.f);
  float r2 = rsqrtf(ss * (1.f / 256.f) - m2 * m2 + 1e-5f);
  #pragma unroll 4
  for (int ci = 0; ci < 64; ci++) {
    int c = q * 64 + ci;
    float m3 = stats3[(b * Cn + c) * 2 + 0];
    float r3 = stats3[(b * Cn + c) * 2 + 1];
    float xv = x[((size_t)b * Cn + c) * Nn + n];
    float tv = t3[((size_t)b * Cn + c) * Nn + n];
    float xc = (tv - m3) * r3 + xv;
    xc = xc >= 0.f ? xc : 0.01f * xc;
    float v = xc + posT[(size_t)c * Nn + n];
    float o = (v - m2) * r2 * g[c] + beta[c];
    T[lane][c] = f2bf(o);
  }
  __syncthreads();
  {
    int rn = t >> 2, cs = (t & 3) * 64;
    unsigned short* dst = xcnbf + ((size_t)b * Nn + n0 + rn) * 256 + cs;
    #pragma unroll
    for (int i = 0; i < 8; i++) *(us8v*)(dst + i * 8) = *(const us8v*)(&T[rn][cs + i * 8]);
  }
}

// ---------------- Q GEMM (bf16 MFMA): C[j][tok], out q_bf [n][256] + qsq ----
__global__ __launch_bounds__(256) void k_gemm_q(
    const unsigned short* __restrict__ Aw,   // wqT [256][256]
    const unsigned short* __restrict__ Bx,   // xnbf [b][n][256]
    unsigned short* __restrict__ qo,         // [b][n][256]
    float* __restrict__ qsq) {
  __shared__ char lds[24576];
  int b = blockIdx.z, n0 = blockIdx.x * 128, j0 = blockIdx.y * 64;
  int t = threadIdx.x, lane = t & 63, wid = t >> 6;
  int wj = wid >> 1, wt = wid & 1;
  f32x4 acc[2][4];
  #pragma unroll
  for (int i = 0; i < 2; i++)
    #pragma unroll
    for (int j = 0; j < 4; j++) acc[i][j] = (f32x4){0.f, 0.f, 0.f, 0.f};
  for (int k0 = 0; k0 < 256; k0 += 64) {
    {
      int r = t >> 2, off = (t & 3) * 16;
      const unsigned short* ga = Aw + (size_t)(j0 + r) * 256 + k0 + off;
      #pragma unroll
      for (int i = 0; i < 2; i++)
        *(us8v*)(lds + r * 128 + ((off * 2 + 16 * i) ^ ((r & 7) << 4))) = *(const us8v*)(ga + i * 8);
      int rb = t >> 1, offb = (t & 1) * 32;
      const unsigned short* gb = Bx + ((size_t)b * Nn + n0 + rb) * 256 + k0 + offb;
      #pragma unroll
      for (int i = 0; i < 4; i++)
        *(us8v*)(lds + 8192 + rb * 128 + ((offb * 2 + 16 * i) ^ ((rb & 7) << 4))) = *(const us8v*)(gb + i * 8);
    }
    __syncthreads();
    #pragma unroll
    for (int ks = 0; ks < 2; ks++) {
      int kb = ks * 64 + (lane >> 4) * 16;
      bf16x8 af[2], bfr[4];
      #pragma unroll
      for (int mt = 0; mt < 2; mt++) {
        int row = wj * 32 + mt * 16 + (lane & 15);
        af[mt] = *(bf16x8*)(lds + row * 128 + (kb ^ ((row & 7) << 4)));
      }
      #pragma unroll
      for (int tt = 0; tt < 4; tt++) {
        int row = wt * 64 + tt * 16 + (lane & 15);
        bfr[tt] = *(bf16x8*)(lds + 8192 + row * 128 + (kb ^ ((row & 7) << 4)));
      }
      #pragma unroll
      for (int mt = 0; mt < 2; mt++)
        #pragma unroll
        for (int tt = 0; tt < 4; tt++)
          acc[mt][tt] = __builtin_amdgcn_mfma_f32_16x16x32_bf16(af[mt], bfr[tt], acc[mt][tt], 0, 0, 0);
    }
    __syncthreads();
  }
  // qsq: per-column sum of squares over this block's 128 tokens
  #pragma unroll
  for (int mt = 0; mt < 2; mt++)
    #pragma unroll
    for (int r = 0; r < 4; r++) {
      float v = 0.f;
      #pragma unroll
      for (int tt = 0; tt < 4; tt++) { float e = acc[mt][tt][r]; v = fmaf(e, e, v); }
      #pragma unroll
      for (int m = 1; m < 16; m <<= 1) v += __shfl_xor(v, m);
      if ((lane & 15) == 0)
        atomicAdd(&qsq[b * Cn + j0 + wj * 32 + mt * 16 + (lane >> 4) * 4 + r], v);
    }
  // pack -> O[tok][j] bf16
  unsigned short* O = (unsigned short*)lds;  // [128][72]
  #pragma unroll
  for (int mt = 0; mt < 2; mt++)
    #pragma unroll
    for (int tt = 0; tt < 4; tt++) {
      int tok = wt * 64 + tt * 16 + (lane & 15);
      int jb = wj * 32 + mt * 16 + ((lane >> 4) << 2);
      uint2 v;
      v.x = pk2(acc[mt][tt][0], acc[mt][tt][1]);
      v.y = pk2(acc[mt][tt][2], acc[mt][tt][3]);
      *(uint2*)(O + tok * 72 + jb) = v;
    }
  __syncthreads();
  int tok = t >> 1, js = (t & 1) * 32;
  unsigned short* dst = qo + ((size_t)b * Nn + n0 + tok) * 256 + j0 + js;
  #pragma unroll
  for (int i = 0; i < 4; i++) *(us8v*)(dst + i * 8) = *(const us8v*)(O + tok * 72 + js + i * 8);
}

// ---------------- xe split-K partial: xe[b,c,p] = sum_n xnf[b,c,n]*w_e[n,p] --
__global__ __launch_bounds__(256) void k_xe_partial(const float* __restrict__ A,
                                                    const float* __restrict__ We,
                                                    float* __restrict__ part) {
  int chunk = blockIdx.x, ct = blockIdx.y, b = blockIdx.z;
  int c0 = ct * 64, nb = chunk * 256;
  __shared__ float As[64][17];
  __shared__ float Ws[16][64];
  int t = threadIdx.x, tx = t & 15, ty = t >> 4;
  float acc[4][4] = {};
  const float* Ab = A + (size_t)b * Cn * Nn;
  for (int k0 = 0; k0 < 256; k0 += 16) {
    {
      int cc = t >> 2, kk0 = (t & 3) * 4;
      float4 v = *(const float4*)(Ab + (size_t)(c0 + cc) * Nn + nb + k0 + kk0);
      As[cc][kk0 + 0] = v.x; As[cc][kk0 + 1] = v.y;
      As[cc][kk0 + 2] = v.z; As[cc][kk0 + 3] = v.w;
    }
    *(float4*)(&Ws[ty][tx * 4]) = *(const float4*)(We + (size_t)(nb + k0 + ty) * Pn + tx * 4);
    __syncthreads();
    #pragma unroll
    for (int kk = 0; kk < 16; kk++) {
      float a_[4], w_[4];
      #pragma unroll
      for (int i = 0; i < 4; i++) a_[i] = As[ty * 4 + i][kk];
      float4 wv = *(const float4*)(&Ws[kk][tx * 4]);
      w_[0] = wv.x; w_[1] = wv.y; w_[2] = wv.z; w_[3] = wv.w;
      #pragma unroll
      for (int i = 0; i < 4; i++)
        #pragma unroll
        for (int j = 0; j < 4; j++) acc[i][j] = fmaf(a_[i], w_[j], acc[i][j]);
    }
    __syncthreads();
  }
  #pragma unroll
  for (int i = 0; i < 4; i++) {
    float4 v = {acc[i][0], acc[i][1], acc[i][2], acc[i][3]};
    *(float4*)(part + (((size_t)(b * NCH + chunk) * Cn + c0 + ty * 4 + i) * Pn) + tx * 4) = v;
  }
}

__global__ __launch_bounds__(256) void k_xe_reduce(const float* __restrict__ part,
                                                   float* __restrict__ xe) {
  int i = blockIdx.x * 256 + threadIdx.x;     // B*C*P = 32768
  int b = i / (Cn * Pn);
  int cp = i % (Cn * Pn);
  float s = 0.f;
  for (int ch = 0; ch < NCH; ch++) s += part[(size_t)(b * NCH + ch) * Cn * Pn + cp];
  xe[i] = s;
}

// ---------------- kv proj -> kpT (scale*T folded, [b][h][p][d]) / vp [b][h][d][p]
__global__ __launch_bounds__(256) void k_kvproj(const float* __restrict__ xe,
                                                const float* __restrict__ wqkv,
                                                const float* __restrict__ be,
                                                const float* __restrict__ qsq,
                                                const float* __restrict__ temp,
                                                unsigned short* __restrict__ kvp) {
  int hd = blockIdx.x * 4 + (threadIdx.x >> 6);
  int kv = blockIdx.y, b = blockIdx.z;
  int p = threadIdx.x & 63;
  int col = (kv + 1) * Cn + hd;
  float acc = be[p];
  for (int c = 0; c < Cn; c++)
    acc = fmaf(xe[((size_t)b * Cn + c) * Pn + p], wqkv[(size_t)c * 768 + col], acc);
  int h = hd >> 6, d = hd & 63;
  if (kv == 0) {
    float sc = 1.f / fmaxf(sqrtf(qsq[b * Cn + hd]), 1e-12f);
    acc *= sc * temp[h];
    kvp[((size_t)(b * 4 + h)) * 4096 + p * 64 + d] = f2bf(acc);
  } else {
    kvp[32768 + ((size_t)(b * 4 + h)) * 4096 + d * 64 + p] = f2bf(acc);
  }
}

// ---------------- pooled partials over token chunks ----------------
__global__ __launch_bounds__(256) void k_pooled_part(const unsigned short* __restrict__ xcn,
                                                     const float* __restrict__ wpool,
                                                     float* __restrict__ part) {
  int ch = blockIdx.x, b = blockIdx.y, t = threadIdx.x;
  float acc = 0.f;
  for (int i = 0; i < 64; i++) {
    int n = ch * 64 + i;
    float v = bf2f(xcn[((size_t)b * Nn + n) * 256 + t]);
    acc = fmaf(v, wpool[n], acc);
  }
  part[((size_t)ch * 2 + b) * 256 + t] = acc;
}

// ---------------- gate = sigmoid(relu(pooled @ wfc1) @ wfc2) ----------------
__global__ __launch_bounds__(256) void k_gate(const float* __restrict__ part,
                                              const float* __restrict__ bpool,
                                              const float* __restrict__ wfc1,
                                              const float* __restrict__ wfc2,
                                              float* __restrict__ gate) {
  int b = blockIdx.x, t = threadIdx.x;
  float s = bpool[0];
  for (int ch = 0; ch < 216; ch++) s += part[((size_t)ch * 2 + b) * 256 + t];
  __shared__ float pl[256], h1[64];
  pl[t] = s;
  __syncthreads();
  if (t < 64) {
    float a = 0.f;
    for (int c = 0; c < Cn; c++) a = fmaf(pl[c], wfc1[c * 64 + t], a);
    h1[t] = fmaxf(a, 0.f);
  }
  __syncthreads();
  float a = 0.f;
  for (int j = 0; j < 64; j++) a = fmaf(h1[j], wfc2[j * Cn + t], a);
  gate[b * Cn + t] = 1.f / (1.f + __expf(-a));
}

// ---------------- w2gT[b][j][c] = gate[b][c]*w_out2[c][j] (bf16) -------------
__global__ __launch_bounds__(256) void k_w2gT(const float* __restrict__ gate,
                                              const float* __restrict__ w2,
                                              unsigned short* __restrict__ w2gT) {
  int j = blockIdx.x, b = blockIdx.y, c = threadIdx.x;
  w2gT[((size_t)b * 128 + j) * 256 + c] = f2bf(gate[b * Cn + c] * w2[(size_t)c * 128 + j]);
}

// ---------------- attention (bf16 MFMA, P=64, per-token softmax) -------------
__global__ __launch_bounds__(128) void k_attn(const unsigned short* __restrict__ qbf,
                                              const unsigned short* __restrict__ kvp,
                                              unsigned short* __restrict__ xsa) {
  __shared__ char lds[16384 + 2 * 9216];
  int nb = blockIdx.x, h = blockIdx.y, b = blockIdx.z;
  int t = threadIdx.x, lane = t & 63, w = t >> 6;
  char* kpT = lds;                 // [64 p][64 d] bf16, swizzled
  char* vp = lds + 8192;           // [64 d][64 p] bf16, swizzled
  unsigned short* P = (unsigned short*)(lds + 16384 + w * 9216);  // per-wave [64 tok][72]
  const unsigned short* kg = kvp + ((size_t)(b * 4 + h)) * 4096;
  const unsigned short* vg = kvp + 32768 + ((size_t)(b * 4 + h)) * 4096;
  {
    int r = t >> 1, off = (t & 1) * 32;
    #pragma unroll
    for (int i = 0; i < 4; i++) {
      *(us8v*)(kpT + r * 128 + ((off * 2 + 16 * i) ^ ((r & 7) << 4))) = *(const us8v*)(kg + r * 64 + off + i * 8);
      *(us8v*)(vp + r * 128 + ((off * 2 + 16 * i) ^ ((r & 7) << 4))) = *(const us8v*)(vg + r * 64 + off + i * 8);
    }
  }
  __syncthreads();
  int n0 = nb * 128 + w * 64;
  // ---- QK^T: C[p][tok] ----
  bf16x8 qf[4][2];
  #pragma unroll
  for (int tt = 0; tt < 4; tt++)
    #pragma unroll
    for (int ks = 0; ks < 2; ks++) {
      int n = n0 + tt * 16 + (lane & 15);
      qf[tt][ks] = *(const bf16x8*)(qbf + ((size_t)b * Nn + n) * 256 + h * 64 + ks * 32 + (lane >> 4) * 8);
    }
  f32x4 s[4][4];
  #pragma unroll
  for (int i = 0; i < 4; i++)
    #pragma unroll
    for (int j = 0; j < 4; j++) s[i][j] = (f32x4){0.f, 0.f, 0.f, 0.f};
  #pragma unroll
  for (int ks = 0; ks < 2; ks++) {
    int kb = ks * 64 + (lane >> 4) * 16;
    #pragma unroll
    for (int mt = 0; mt < 4; mt++) {
      int row = mt * 16 + (lane & 15);
      bf16x8 a = *(bf16x8*)(kpT + row * 128 + (kb ^ ((row & 7) << 4)));
      #pragma unroll
      for (int tt = 0; tt < 4; tt++)
        s[mt][tt] = __builtin_amdgcn_mfma_f32_16x16x32_bf16(a, qf[tt][ks], s[mt][tt], 0, 0, 0);
    }
  }
  // ---- softmax over p (rows) per token column ----
  #pragma unroll
  for (int tt = 0; tt < 4; tt++) {
    float mx = -1e30f;
    #pragma unroll
    for (int mt = 0; mt < 4; mt++)
      #pragma unroll
      for (int r = 0; r < 4; r++) mx = fmaxf(mx, s[mt][tt][r]);
    mx = fmaxf(mx, __shfl_xor(mx, 16));
    mx = fmaxf(mx, __shfl_xor(mx, 32));
    float den = 0.f;
    #pragma unroll
    for (int mt = 0; mt < 4; mt++)
      #pragma unroll
      for (int r = 0; r < 4; r++) {
        float e = __expf(s[mt][tt][r] - mx);
        s[mt][tt][r] = e; den += e;
      }
    den += __shfl_xor(den, 16);
    den += __shfl_xor(den, 32);
    float inv = 1.f / den;
    #pragma unroll
    for (int mt = 0; mt < 4; mt++)
      #pragma unroll
      for (int r = 0; r < 4; r++) s[mt][tt][r] *= inv;
  }
  // ---- P[tok][p] bf16 (per-wave buffer) ----
  #pragma unroll
  for (int mt = 0; mt < 4; mt++)
    #pragma unroll
    for (int tt = 0; tt < 4; tt++) {
      int tok = tt * 16 + (lane & 15);
      int pb = mt * 16 + ((lane >> 4) << 2);
      uint2 v;
      v.x = pk2(s[mt][tt][0], s[mt][tt][1]);
      v.y = pk2(s[mt][tt][2], s[mt][tt][3]);
      *(uint2*)(P + tok * 72 + pb) = v;
    }
  // ---- PV: C[tok][d] = P[tok][p] x vp[d][p]^T ----
  bf16x8 pf[4][2];
  #pragma unroll
  for (int mt = 0; mt < 4; mt++)
    #pragma unroll
    for (int ks = 0; ks < 2; ks++)
      pf[mt][ks] = *(const bf16x8*)(P + (mt * 16 + (lane & 15)) * 72 + ks * 32 + (lane >> 4) * 8);
  f32x4 o[4][4];
  #pragma unroll
  for (int i = 0; i < 4; i++)
    #pragma unroll
    for (int j = 0; j < 4; j++) o[i][j] = (f32x4){0.f, 0.f, 0.f, 0.f};
  #pragma unroll
  for (int ks = 0; ks < 2; ks++) {
    int kb = ks * 64 + (lane >> 4) * 16;
    #pragma unroll
    for (int nt = 0; nt < 4; nt++) {
      int row = nt * 16 + (lane & 15);
      bf16x8 bfv = *(bf16x8*)(vp + row * 128 + (kb ^ ((row & 7) << 4)));
      #pragma unroll
      for (int mt = 0; mt < 4; mt++)
        o[mt][nt] = __builtin_amdgcn_mfma_f32_16x16x32_bf16(pf[mt][ks], bfv, o[mt][nt], 0, 0, 0);
    }
  }
  // ---- OT[d][tok] bf16 into P-space, then coalesced flat-scramble write ----
  #pragma unroll
  for (int mt = 0; mt < 4; mt++)
    #pragma unroll
    for (int nt = 0; nt < 4; nt++) {
      int d = nt * 16 + (lane & 15);
      int tb = mt * 16 + ((lane >> 4) << 2);
      uint2 v;
      v.x = pk2(o[mt][nt][0], o[mt][nt][1]);
      v.y = pk2(o[mt][nt][2], o[mt][nt][3]);
      *(uint2*)(P + d * 72 + tb) = v;
    }
  // lane = d; flat index (d*4+h)*N + n  (reinterpreted later as [N][C])
  size_t fb = (size_t)b * Cn * Nn + ((size_t)(lane * 4 + h)) * Nn + n0;
  #pragma unroll
  for (int k = 0; k < 8; k++)
    *(us8v*)(xsa + fb + k * 8) = *(const us8v*)(P + lane * 72 + k * 8);
}

// ---------------- out GEMM (bf16 MFMA) + fused epilogue/transpose ------------
__global__ __launch_bounds__(256) void k_gemm_out(
    const unsigned short* __restrict__ Aw, size_t a_bstride,
    const unsigned short* __restrict__ Bx,
    const float* __restrict__ bias, int cbase,
    const float* __restrict__ xnf, const float* __restrict__ gamma,
    float* __restrict__ outp) {
  __shared__ char lds[33792];
  int b = blockIdx.z, n0 = blockIdx.x * 128, j0 = blockIdx.y * 64;
  int t = threadIdx.x, lane = t & 63, wid = t >> 6;
  int wj = wid >> 1, wt = wid & 1;
  const unsigned short* Ab = Aw + a_bstride * b;
  f32x4 acc[2][4];
  #pragma unroll
  for (int i = 0; i < 2; i++)
    #pragma unroll
    for (int j = 0; j < 4; j++) acc[i][j] = (f32x4){0.f, 0.f, 0.f, 0.f};
  for (int k0 = 0; k0 < 256; k0 += 64) {
    {
      int r = t >> 2, off = (t & 3) * 16;
      const unsigned short* ga = Ab + (size_t)(j0 + r) * 256 + k0 + off;
      #pragma unroll
      for (int i = 0; i < 2; i++)
        *(us8v*)(lds + r * 128 + ((off * 2 + 16 * i) ^ ((r & 7) << 4))) = *(const us8v*)(ga + i * 8);
      int rb = t >> 1, offb = (t & 1) * 32;
      const unsigned short* gb = Bx + ((size_t)b * Nn + n0 + rb) * 256 + k0 + offb;
      #pragma unroll
      for (int i = 0; i < 4; i++)
        *(us8v*)(lds + 8192 + rb * 128 + ((offb * 2 + 16 * i) ^ ((rb & 7) << 4))) = *(const us8v*)(gb + i * 8);
    }
    __syncthreads();
    #pragma unroll
    for (int ks = 0; ks < 2; ks++) {
      int kb = ks * 64 + (lane >> 4) * 16;
      bf16x8 af[2], bfr[4];
      #pragma unroll
      for (int mt = 0; mt < 2; mt++) {
        int row = wj * 32 + mt * 16 + (lane & 15);
        af[mt] = *(bf16x8*)(lds + row * 128 + (kb ^ ((row & 7) << 4)));
      }
      #pragma unroll
      for (int tt = 0; tt < 4; tt++) {
        int row = wt * 64 + tt * 16 + (lane & 15);
        bfr[tt] = *(bf16x8*)(lds + 8192 + row * 128 + (kb ^ ((row & 7) << 4)));
      }
      #pragma unroll
      for (int mt = 0; mt < 2; mt++)
        #pragma unroll
        for (int tt = 0; tt < 4; tt++)
          acc[mt][tt] = __builtin_amdgcn_mfma_f32_16x16x32_bf16(af[mt], bfr[tt], acc[mt][tt], 0, 0, 0);
    }
    __syncthreads();
  }
  float* OT = (float*)lds;  // [64 j][132 tok]
  #pragma unroll
  for (int mt = 0; mt < 2; mt++)
    #pragma unroll
    for (int tt = 0; tt < 4; tt++)
      #pragma unroll
      for (int r = 0; r < 4; r++) {
        int j = wj * 32 + mt * 16 + (lane >> 4) * 4 + r;
        int tok = wt * 64 + tt * 16 + (lane & 15);
        OT[j * 132 + tok] = acc[mt][tt][r];
      }
  __syncthreads();
  int jj = t >> 2, ts = (t & 3) * 32;
  int c = cbase + j0 + jj;
  float gm = gamma[c], bi = bias[j0 + jj];
  const float* xn = xnf + ((size_t)b * Cn + c) * Nn + n0 + ts;
  float* op = outp + ((size_t)b * Cn + c) * Nn + n0 + ts;
  #pragma unroll
  for (int i = 0; i < 8; i++) {
    f32x4 v = *(const f32x4*)(&OT[jj * 132 + ts + i * 4]);
    f32x4 xv = *(const f32x4*)(xn + i * 4);
    f32x4 ov;
    #pragma unroll
    for (int e = 0; e < 4; e++) ov[e] = xv[e] + gm * (v[e] + bi);
    *(f32x4*)(op + i * 4) = ov;
  }
}

extern "C" void kernel_launch(void* const* d_in, const int* in_sizes, int n_in,
                              void* d_out, int out_size, void* d_ws, size_t ws_size,
                              hipStream_t stream) {
  const float* x      = (const float*)d_in[0];
  const float* pos    = (const float*)d_in[1];
  const float* ln_g   = (const float*)d_in[2];
  const float* ln_b   = (const float*)d_in[3];
  const float* gamma  = (const float*)d_in[4];
  const float* temp2  = (const float*)d_in[5];
  const float* w_qkv  = (const float*)d_in[6];
  const float* w_e    = (const float*)d_in[7];
  const float* b_e    = (const float*)d_in[8];
  const float* w_pool = (const float*)d_in[9];
  const float* b_pool = (const float*)d_in[10];
  const float* w_fc1  = (const float*)d_in[11];
  const float* w_fc2  = (const float*)d_in[12];
  const float* w_out1 = (const float*)d_in[13];
  const float* b_out1 = (const float*)d_in[14];
  const float* w_out2 = (const float*)d_in[15];
  const float* b_out2 = (const float*)d_in[16];
  const float* w_c1   = (const float*)d_in[17];
  const float* b_c1   = (const float*)d_in[18];
  const float* w_c2   = (const float*)d_in[19];
  const float* b_c2   = (const float*)d_in[20];
  (void)in_sizes; (void)n_in; (void)out_size; (void)ws_size;
  float* out = (float*)d_out;

  const size_t SZ = (size_t)Bn * Cn * Nn;   // 7,077,888
  const size_t NC = (size_t)Nn * Cn;        // 3,538,944
  const size_t XEP = (size_t)NCH * Bn * Cn * Pn;  // 1,769,472
  char* base = (char*)d_ws;
  size_t off = 0;
  auto alloc = [&](size_t bytes) { void* p = base + off; off += (bytes + 255) & ~(size_t)255; return p; };
  float* t3     = (float*)alloc(SZ * 4);
  float* xnf    = (float*)alloc(SZ * 4);
  float* posT   = (float*)alloc(NC * 4);
  float* xepart = (float*)alloc(XEP * 4);
  unsigned short* xnbf  = (unsigned short*)alloc(SZ * 2);
  unsigned short* xcnbf = (unsigned short*)alloc(SZ * 2);
  char* alias = (char*)alloc(SZ * 4);           // t1 (early) == qbf + xsabf (late)
  float* t1 = (float*)alias;
  unsigned short* qbf   = (unsigned short*)alias;
  unsigned short* xsabf = (unsigned short*)alias + SZ;
  float* stats1 = (float*)alloc(1024 * 4);
  float* stats3 = (float*)alloc(1024 * 4);
  float* xe     = (float*)alloc(32768 * 4);
  float* qsq    = (float*)alloc(512 * 4);
  float* ppart  = (float*)alloc(110592 * 4);
  float* gateb  = (float*)alloc(512 * 4);
  unsigned short* kvp  = (unsigned short*)alloc(65536 * 2);
  unsigned short* w2gt = (unsigned short*)alloc(65536 * 2);
  unsigned short* wqT  = (unsigned short*)alloc(65536 * 2);
  unsigned short* w1T  = (unsigned short*)alloc(32768 * 2);

  k_wcvt<<<dim3(384), 256, 0, stream>>>(w_qkv, w_out1, wqT, w1T);
  k_transpose_pos<<<dim3(216, 4), 256, 0, stream>>>(pos, posT);
  k_gconv<false><<<dim3(NCH, Gn, Bn), 256, 0, stream>>>(x, w_c1, b_c1, nullptr, t1);
  k_rowstats<<<dim3(Bn * Cn), 256, 0, stream>>>(t1, stats1);
  k_gconv<true><<<dim3(NCH, Gn, Bn), 256, 0, stream>>>(t1, w_c2, b_c2, stats1, t3);
  k_rowstats<<<dim3(Bn * Cn), 256, 0, stream>>>(t3, stats3);
  k_fused_ln<<<dim3(216, Bn), 256, 0, stream>>>(x, t3, posT, stats3, ln_g, ln_b, xnf, xnbf, xcnbf);
  hipMemsetAsync(qsq, 0, 512 * 4, stream);
  k_gemm_q<<<dim3(108, 4, Bn), 256, 0, stream>>>(wqT, xnbf, qbf, qsq);
  k_xe_partial<<<dim3(NCH, 4, Bn), 256, 0, stream>>>(xnf, w_e, xepart);
  k_xe_reduce<<<dim3(128), 256, 0, stream>>>(xepart, xe);
  k_kvproj<<<dim3(64, 2, Bn), 256, 0, stream>>>(xe, w_qkv, b_e, qsq, temp2, kvp);
  k_pooled_part<<<dim3(216, Bn), 256, 0, stream>>>(xcnbf, w_pool, ppart);
  k_gate<<<dim3(Bn), 256, 0, stream>>>(ppart, b_pool, w_fc1, w_fc2, gateb);
  k_w2gT<<<dim3(128, Bn), 256, 0, stream>>>(gateb, w_out2, w2gt);
  k_attn<<<dim3(108, NHn, Bn), 128, 0, stream>>>(qbf, kvp, xsabf);
  k_gemm_out<<<dim3(108, 2, Bn), 256, 0, stream>>>(w1T, 0, xsabf, b_out1, 0, xnf, gamma, out);
  k_gemm_out<<<dim3(108, 2, Bn), 256, 0, stream>>>(w2gt, (size_t)128 * 256, xcnbf, b_out2, 128, xnf, gamma, out);
}